// Round 1
// baseline (21561.107 us; speedup 1.0000x reference)
//
#include <hip/hip_runtime.h>
#include <hip/hip_cooperative_groups.h>

namespace cg = cooperative_groups;

#define T_STEPS 512
#define BATCH   128
#define NN      1024
#define ALPHA_C 0.1f
#define DT_C    0.01f

// d_ws float offsets
#define OFF_BUFA 0
#define OFF_BUFB (BATCH*NN)                      // 131072
#define OFF_PART (2*BATCH*NN)                    // 262144  ([2][128][2][64] f32)
#define OFF_WC   (2*BATCH*NN + 2*BATCH*2*64)     // 294912  ([64][256][16][4] f32 = 4 MB)

// 256 blocks x (16,32) threads. Block b: colgroup g = b&63 (16 n-columns),
// bgroup bb = b>>6 (32 batch rows). 1 output/thread, x1 state in a register.
__launch_bounds__(512, 2)
__global__ void rnn_step_kernel(const float* __restrict__ X,
                                const float* __restrict__ Xpert,
                                const float* __restrict__ popto,
                                const float* __restrict__ hidden0,
                                const float* __restrict__ W_hh,
                                const float* __restrict__ W_ih,
                                const float* __restrict__ W_fb,
                                const float* __restrict__ b_fb,
                                const float* __restrict__ W_out,
                                const float* __restrict__ b_out,
                                const float* __restrict__ mask_fb,
                                const float* __restrict__ mask_rec,
                                float* __restrict__ out,
                                float* __restrict__ ws)
{
    __shared__ float4 Wbuf[2][512];        // [dbuf][k4l*16 + nl]   (8 KB x2)
    __shared__ float  Rbuf[2][32][132];    // [dbuf][b][k(128) pad] (16.9 KB x2)
    __shared__ float  v1s[32][2];

    const int tx  = threadIdx.x;           // 0..15 -> n within colgroup
    const int ty  = threadIdx.y;           // 0..31 -> b within bgroup
    const int tid = ty * 16 + tx;
    const int g   = blockIdx.x & 63;
    const int bb  = blockIdx.x >> 6;
    const int n   = g * 16 + tx;
    const int gb0 = bb * 32;
    const int gb  = gb0 + ty;

    float* bufA = ws + OFF_BUFA;
    float* bufB = ws + OFF_BUFB;
    float* part = ws + OFF_PART;           // [parity][gb][o][g]
    float* Wc   = ws + OFF_WC;             // [g][k4][nl][4]

    // ---- per-thread constants ----
    const float wout0 = W_out[n];
    const float wout1 = W_out[NN + n];
    const float wfb0  = W_fb[n*2+0] * mask_fb[n*2+0];
    const float wfb1  = W_fb[n*2+1] * mask_fb[n*2+1];
    const float wih0  = W_ih[n*3+0];
    const float wih1  = W_ih[n*3+1];
    const float wih2  = W_ih[n*3+2];
    const float bfbv  = b_fb[n];
    const float bo0   = b_out[0], bo1 = b_out[1];

    // ---- phase 0: init state, r1_init -> bufA, vt partials parity 0, Wc fill ----
    float x1 = hidden0[gb*NN + n];
    {
        float r1i = fmaxf(x1, 0.f);
        bufA[gb*NN + n] = r1i;
        float p0 = r1i * wout0, p1 = r1i * wout1;
        #pragma unroll
        for (int m = 1; m < 16; m <<= 1) { p0 += __shfl_xor(p0, m); p1 += __shfl_xor(p1, m); }
        if (tx == 0) {
            part[((0*BATCH + gb)*2 + 0)*64 + g] = p0;
            part[((0*BATCH + gb)*2 + 1)*64 + g] = p1;
        }
    }
    // masked W_hh -> compact k-major float4 layout (once)
    for (int i = 0; i < 8; ++i) {
        int flat = tid + i*512;            // 0..4095 (this WG covers k4 range of bb)
        int k4l = flat >> 6, rem = flat & 63, nl = rem >> 2, j = rem & 3;
        int k4  = bb*64 + k4l;
        int k   = k4*4 + j;
        int row = g*16 + nl;
        Wc[((g*256 + k4)*16 + nl)*4 + j] = W_hh[row*NN + k] * mask_rec[row*NN + k];
    }

    cg::this_grid().sync();

    const float4* WcP   = (const float4*)Wc;
    const int wc_base   = g * 4096;        // 256 k4 * 16 nl per colgroup
    const int b1 = tid >> 5;               // staging rows 0..15
    const int c4 = tid & 31;
    const int b2 = b1 + 16;                // staging rows 16..31
    float4* Wb4 = &Wbuf[0][0];

    const float4* bufA4 = (const float4*)bufA;
    const float4* bufB4 = (const float4*)bufB;
    float* Hout = out + (size_t)T_STEPS * BATCH * 2;
    const float4* hid4 = (const float4*)Hout;

    for (int s = 0; s <= T_STEPS + 1; ++s) {
        // ---- v1 phase: fold previous step's vt partials into v1 ----
        const int pr = s & 1;
        if (tid < 64) {
            int b = tid >> 1, o = tid & 1;
            int gbv = gb0 + b;
            const float4* pp = (const float4*)&part[((pr*BATCH + gbv)*2 + o)*64];
            float sum = 0.f;
            #pragma unroll
            for (int q = 0; q < 16; ++q) { float4 v = pp[q]; sum += v.x + v.y + v.z + v.w; }
            float bo = o ? bo1 : bo0;
            float v1n;
            if (s == 0) {
                v1n = sum + bo;                                   // v1_init
            } else {
                int tp = (s == 1) ? 0 : (s - 2);
                float vt = sum + bo + Xpert[(tp*BATCH + gbv)*2 + o];
                v1n = v1s[b][o] + DT_C * (X[(tp*BATCH + gbv)*7 + 3 + o] - vt);
                if (s >= 2 && g == 0)
                    out[(size_t)(s-2)*BATCH*2 + gbv*2 + o] = v1n; // poserr[s-2]
            }
            v1s[b][o] = v1n;
        }
        __syncthreads();
        if (s > T_STEPS) break;            // epilogue (s==513) only did poserr[511]

        // ---- main step s (warmup s=0, scan j=s-1) ----
        const int cur = (s == 0) ? 0 : (s - 1);
        float fb = 0.f;
        if (s >= 2) fb = v1s[ty][0]*wfb0 + v1s[ty][1]*wfb1;       // j==0 & warmup: zero fb
        const float* Xc = X + (size_t)(cur*BATCH + gb) * 7;
        float extra = fmaf(Xc[0], wih0, fmaf(Xc[1], wih1, fmaf(Xc[2], wih2, bfbv))) + fb
                    + popto[(size_t)cur*BATCH*NN + gb*NN + n];

        const float4* Rsrc = (s == 0) ? bufA4
                           : (s == 1) ? bufB4
                           : (hid4 + (size_t)(s-2) * (BATCH*NN/4));
        const int rb0 = (gb0 + b1)*(NN/4) + c4;
        const int rb1 = (gb0 + b2)*(NN/4) + c4;

        // preload + stage chunk 0
        float4 wreg  = WcP[wc_base + tid];
        float4 rreg0 = Rsrc[rb0];
        float4 rreg1 = Rsrc[rb1];
        Wb4[tid] = wreg;
        *(float4*)&Rbuf[0][b1][c4*4] = rreg0;
        *(float4*)&Rbuf[0][b2][c4*4] = rreg1;
        __syncthreads();

        float4 acc = make_float4(0.f, 0.f, 0.f, 0.f);
        for (int c = 0; c < 8; ++c) {
            const int buf = c & 1;
            if (c < 7) {                    // issue next chunk's global loads early
                wreg  = WcP[wc_base + (c+1)*512 + tid];
                rreg0 = Rsrc[rb0 + (c+1)*32];
                rreg1 = Rsrc[rb1 + (c+1)*32];
            }
            #pragma unroll
            for (int k4 = 0; k4 < 32; ++k4) {
                float4 w = Wb4[buf*512 + k4*16 + tx];             // bcast across ty
                float4 r = *(const float4*)&Rbuf[buf][ty][k4*4];  // bcast across tx
                acc.x = fmaf(w.x, r.x, acc.x);
                acc.y = fmaf(w.y, r.y, acc.y);
                acc.z = fmaf(w.z, r.z, acc.z);
                acc.w = fmaf(w.w, r.w, acc.w);
            }
            if (c < 7) {
                Wb4[(buf^1)*512 + tid] = wreg;
                *(float4*)&Rbuf[buf^1][b1][c4*4] = rreg0;
                *(float4*)&Rbuf[buf^1][b2][c4*4] = rreg1;
            }
            __syncthreads();
        }

        float pre = (acc.x + acc.y) + (acc.z + acc.w) + extra;
        x1 = x1 + ALPHA_C * (pre - x1);
        float r1 = fmaxf(x1, 0.f);
        float* dst = (s == 0) ? bufB : (Hout + (size_t)(s-1)*BATCH*NN);
        dst[gb*NN + n] = r1;                                      // hidden1[s-1] for s>=1

        // vt partials for this step (parity pw)
        {
            float p0 = r1 * wout0, p1 = r1 * wout1;
            #pragma unroll
            for (int m = 1; m < 16; m <<= 1) { p0 += __shfl_xor(p0, m); p1 += __shfl_xor(p1, m); }
            if (tx == 0) {
                const int pw = (s + 1) & 1;
                part[((pw*BATCH + gb)*2 + 0)*64 + g] = p0;
                part[((pw*BATCH + gb)*2 + 1)*64 + g] = p1;
            }
        }
        cg::this_grid().sync();
    }
}

extern "C" void kernel_launch(void* const* d_in, const int* in_sizes, int n_in,
                              void* d_out, int out_size, void* d_ws, size_t ws_size,
                              hipStream_t stream) {
    (void)in_sizes; (void)n_in; (void)out_size; (void)ws_size;
    const float* X        = (const float*)d_in[0];
    const float* Xpert    = (const float*)d_in[1];
    const float* popto    = (const float*)d_in[2];
    const float* hidden0  = (const float*)d_in[3];
    const float* W_hh     = (const float*)d_in[4];
    const float* W_ih     = (const float*)d_in[5];
    const float* W_fb     = (const float*)d_in[6];
    const float* b_fb     = (const float*)d_in[7];
    const float* W_out    = (const float*)d_in[8];
    const float* b_out    = (const float*)d_in[9];
    const float* mask_fb  = (const float*)d_in[10];
    const float* mask_rec = (const float*)d_in[11];
    float* out = (float*)d_out;
    float* ws  = (float*)d_ws;

    void* args[] = { &X, &Xpert, &popto, &hidden0, &W_hh, &W_ih, &W_fb, &b_fb,
                     &W_out, &b_out, &mask_fb, &mask_rec, &out, &ws };
    hipLaunchCooperativeKernel((const void*)rnn_step_kernel, dim3(256), dim3(16, 32, 1),
                               args, 0, stream);
}

// Round 3
// 11386.423 us; speedup vs baseline: 1.8936x; 1.8936x over previous
//
#include <hip/hip_runtime.h>
#include <hip/hip_cooperative_groups.h>

namespace cg = cooperative_groups;

#define T_STEPS 512
#define BATCH   128
#define NN      1024
#define ALPHA_C 0.1f
#define DT_C    0.01f

// d_ws float offsets
#define OFF_BUFA 0
#define OFF_BUFB (BATCH*NN)                      // 131072
#define OFF_PART (2*BATCH*NN)                    // 262144  ([2][128][2][64] f32)
#define OFF_WC   (2*BATCH*NN + 2*BATCH*2*64)     // 294912  ([64][256][16][4] f32 = 4 MB)
#define OFF_BAR  (OFF_WC + NN*NN)                // barrier counters (4 x 128B-spaced)

// Lightweight monotonic-counter barrier for a group of blocks.
// Arrive: release add. Wait: acquire spin (final load syncs-with all releases).
// Counter never resets (monotonic target), so no reinit races.
__device__ __forceinline__ void group_barrier(unsigned* cnt, unsigned target, int tid) {
    __syncthreads();
    if (tid == 0) {
        __hip_atomic_fetch_add(cnt, 1u, __ATOMIC_RELEASE, __HIP_MEMORY_SCOPE_AGENT);
        while (__hip_atomic_load(cnt, __ATOMIC_ACQUIRE, __HIP_MEMORY_SCOPE_AGENT) < target)
            __builtin_amdgcn_s_sleep(1);
    }
    __syncthreads();
}

// 256 blocks x (16,32) threads. Block b: colgroup g = b&63 (16 n-columns),
// bgroup bb = b>>6 (32 batch rows). 1 output/thread, x1 state in a register.
// Per-step sync: per-bb 64-block custom barrier (cross-block dataflow never
// crosses bb after init). cg grid sync used once at init (Wc fill crosses bb).
__launch_bounds__(512, 2)
__global__ void rnn_step_kernel(const float* __restrict__ X,
                                const float* __restrict__ Xpert,
                                const float* __restrict__ popto,
                                const float* __restrict__ hidden0,
                                const float* __restrict__ W_hh,
                                const float* __restrict__ W_ih,
                                const float* __restrict__ W_fb,
                                const float* __restrict__ b_fb,
                                const float* __restrict__ W_out,
                                const float* __restrict__ b_out,
                                const float* __restrict__ mask_fb,
                                const float* __restrict__ mask_rec,
                                float* __restrict__ out,
                                float* __restrict__ ws)
{
    __shared__ float4 Wbuf[2][512];        // [dbuf][k4l*16 + nl]   (8 KB x2)
    __shared__ float  Rbuf[2][32][132];    // [dbuf][b][k(128) pad] (16.9 KB x2)
    __shared__ float  v1s[32][2];

    const int tx  = threadIdx.x;           // 0..15 -> n within colgroup
    const int ty  = threadIdx.y;           // 0..31 -> b within bgroup
    const int tid = ty * 16 + tx;
    const int g   = blockIdx.x & 63;
    const int bb  = blockIdx.x >> 6;
    const int n   = g * 16 + tx;
    const int gb0 = bb * 32;
    const int gb  = gb0 + ty;

    float* bufA = ws + OFF_BUFA;
    float* bufB = ws + OFF_BUFB;
    float* part = ws + OFF_PART;           // [parity][gb][o][g]
    float* Wc   = ws + OFF_WC;             // [g][k4][nl][4]
    unsigned* barArea = (unsigned*)(ws + OFF_BAR);
    unsigned* myBar   = barArea + bb * 32; // 128B apart per bb-group

    // Block 0 zeroes the barrier counters (ws is poisoned 0xAA by the harness).
    // Visible to all after the init grid sync.
    if (blockIdx.x == 0 && tid < 4)
        __hip_atomic_store(barArea + tid * 32, 0u, __ATOMIC_RELAXED, __HIP_MEMORY_SCOPE_AGENT);

    // ---- per-thread constants ----
    const float wout0 = W_out[n];
    const float wout1 = W_out[NN + n];
    const float wfb0  = W_fb[n*2+0] * mask_fb[n*2+0];
    const float wfb1  = W_fb[n*2+1] * mask_fb[n*2+1];
    const float wih0  = W_ih[n*3+0];
    const float wih1  = W_ih[n*3+1];
    const float wih2  = W_ih[n*3+2];
    const float bfbv  = b_fb[n];
    const float bo0   = b_out[0], bo1 = b_out[1];

    // ---- phase 0: init state, r1_init -> bufA, vt partials parity 0, Wc fill ----
    float x1 = hidden0[gb*NN + n];
    {
        float r1i = fmaxf(x1, 0.f);
        bufA[gb*NN + n] = r1i;
        float p0 = r1i * wout0, p1 = r1i * wout1;
        #pragma unroll
        for (int m = 1; m < 16; m <<= 1) { p0 += __shfl_xor(p0, m); p1 += __shfl_xor(p1, m); }
        if (tx == 0) {
            part[((0*BATCH + gb)*2 + 0)*64 + g] = p0;
            part[((0*BATCH + gb)*2 + 1)*64 + g] = p1;
        }
    }
    // masked W_hh -> compact k-major float4 layout (once)
    for (int i = 0; i < 8; ++i) {
        int flat = tid + i*512;            // 0..4095 (this WG covers k4 range of bb)
        int k4l = flat >> 6, rem = flat & 63, nl = rem >> 2, j = rem & 3;
        int k4  = bb*64 + k4l;
        int k   = k4*4 + j;
        int row = g*16 + nl;
        Wc[((g*256 + k4)*16 + nl)*4 + j] = W_hh[row*NN + k] * mask_rec[row*NN + k];
    }

    cg::this_grid().sync();                // once: covers Wc (cross-bb) + counters

    const float4* WcP   = (const float4*)Wc;
    const int wc_base   = g * 4096;        // 256 k4 * 16 nl per colgroup
    const int b1 = tid >> 5;               // staging rows 0..15
    const int c4 = tid & 31;
    const int b2 = b1 + 16;                // staging rows 16..31
    float4* Wb4 = &Wbuf[0][0];

    const float4* bufA4 = (const float4*)bufA;
    const float4* bufB4 = (const float4*)bufB;
    float* Hout = out + (size_t)T_STEPS * BATCH * 2;
    const float4* hid4 = (const float4*)Hout;

    for (int s = 0; s <= T_STEPS + 1; ++s) {
        // ---- v1 phase: fold previous step's vt partials into v1 ----
        const int pr = s & 1;
        if (tid < 64) {
            int b = tid >> 1, o = tid & 1;
            int gbv = gb0 + b;
            const float4* pp = (const float4*)&part[((pr*BATCH + gbv)*2 + o)*64];
            float sum = 0.f;
            #pragma unroll
            for (int q = 0; q < 16; ++q) { float4 v = pp[q]; sum += v.x + v.y + v.z + v.w; }
            float bo = o ? bo1 : bo0;
            float v1n;
            if (s == 0) {
                v1n = sum + bo;                                   // v1_init
            } else {
                int tp = (s == 1) ? 0 : (s - 2);
                float vt = sum + bo + Xpert[(tp*BATCH + gbv)*2 + o];
                v1n = v1s[b][o] + DT_C * (X[(tp*BATCH + gbv)*7 + 3 + o] - vt);
                if (s >= 2 && g == 0)
                    out[(size_t)(s-2)*BATCH*2 + gbv*2 + o] = v1n; // poserr[s-2]
            }
            v1s[b][o] = v1n;
        }
        __syncthreads();
        if (s > T_STEPS) break;            // epilogue (s==513) only did poserr[511]

        // ---- main step s (warmup s=0, scan j=s-1) ----
        const int cur = (s == 0) ? 0 : (s - 1);
        float fb = 0.f;
        if (s >= 2) fb = v1s[ty][0]*wfb0 + v1s[ty][1]*wfb1;       // j==0 & warmup: zero fb
        const float* Xc = X + (size_t)(cur*BATCH + gb) * 7;
        float extra = fmaf(Xc[0], wih0, fmaf(Xc[1], wih1, fmaf(Xc[2], wih2, bfbv))) + fb
                    + popto[(size_t)cur*BATCH*NN + gb*NN + n];

        const float4* Rsrc = (s == 0) ? bufA4
                           : (s == 1) ? bufB4
                           : (hid4 + (size_t)(s-2) * (BATCH*NN/4));
        const int rb0 = (gb0 + b1)*(NN/4) + c4;
        const int rb1 = (gb0 + b2)*(NN/4) + c4;

        // preload + stage chunk 0
        float4 wreg  = WcP[wc_base + tid];
        float4 rreg0 = Rsrc[rb0];
        float4 rreg1 = Rsrc[rb1];
        Wb4[tid] = wreg;
        *(float4*)&Rbuf[0][b1][c4*4] = rreg0;
        *(float4*)&Rbuf[0][b2][c4*4] = rreg1;
        __syncthreads();

        float4 acc = make_float4(0.f, 0.f, 0.f, 0.f);
        for (int c = 0; c < 8; ++c) {
            const int buf = c & 1;
            if (c < 7) {                    // issue next chunk's global loads early
                wreg  = WcP[wc_base + (c+1)*512 + tid];
                rreg0 = Rsrc[rb0 + (c+1)*32];
                rreg1 = Rsrc[rb1 + (c+1)*32];
            }
            #pragma unroll
            for (int k4 = 0; k4 < 32; ++k4) {
                float4 w = Wb4[buf*512 + k4*16 + tx];             // bcast across ty
                float4 r = *(const float4*)&Rbuf[buf][ty][k4*4];  // bcast across tx
                acc.x = fmaf(w.x, r.x, acc.x);
                acc.y = fmaf(w.y, r.y, acc.y);
                acc.z = fmaf(w.z, r.z, acc.z);
                acc.w = fmaf(w.w, r.w, acc.w);
            }
            if (c < 7) {
                Wb4[(buf^1)*512 + tid] = wreg;
                *(float4*)&Rbuf[buf^1][b1][c4*4] = rreg0;
                *(float4*)&Rbuf[buf^1][b2][c4*4] = rreg1;
            }
            __syncthreads();
        }

        float pre = (acc.x + acc.y) + (acc.z + acc.w) + extra;
        x1 = x1 + ALPHA_C * (pre - x1);
        float r1 = fmaxf(x1, 0.f);
        float* dst = (s == 0) ? bufB : (Hout + (size_t)(s-1)*BATCH*NN);
        dst[gb*NN + n] = r1;                                      // hidden1[s-1] for s>=1

        // vt partials for this step (parity pw)
        {
            float p0 = r1 * wout0, p1 = r1 * wout1;
            #pragma unroll
            for (int m = 1; m < 16; m <<= 1) { p0 += __shfl_xor(p0, m); p1 += __shfl_xor(p1, m); }
            if (tx == 0) {
                const int pw = (s + 1) & 1;
                part[((pw*BATCH + gb)*2 + 0)*64 + g] = p0;
                part[((pw*BATCH + gb)*2 + 1)*64 + g] = p1;
            }
        }
        // per-bb-group barrier (64 blocks), replaces cg grid sync
        group_barrier(myBar, 64u * (unsigned)(s + 1), tid);
    }
}

extern "C" void kernel_launch(void* const* d_in, const int* in_sizes, int n_in,
                              void* d_out, int out_size, void* d_ws, size_t ws_size,
                              hipStream_t stream) {
    (void)in_sizes; (void)n_in; (void)out_size; (void)ws_size;
    const float* X        = (const float*)d_in[0];
    const float* Xpert    = (const float*)d_in[1];
    const float* popto    = (const float*)d_in[2];
    const float* hidden0  = (const float*)d_in[3];
    const float* W_hh     = (const float*)d_in[4];
    const float* W_ih     = (const float*)d_in[5];
    const float* W_fb     = (const float*)d_in[6];
    const float* b_fb     = (const float*)d_in[7];
    const float* W_out    = (const float*)d_in[8];
    const float* b_out    = (const float*)d_in[9];
    const float* mask_fb  = (const float*)d_in[10];
    const float* mask_rec = (const float*)d_in[11];
    float* out = (float*)d_out;
    float* ws  = (float*)d_ws;

    void* args[] = { &X, &Xpert, &popto, &hidden0, &W_hh, &W_ih, &W_fb, &b_fb,
                     &W_out, &b_out, &mask_fb, &mask_rec, &out, &ws };
    (void)hipLaunchCooperativeKernel((const void*)rnn_step_kernel, dim3(256), dim3(16, 32, 1),
                                     args, 0, stream);
}